// Round 12
// baseline (589.373 us; speedup 1.0000x reference)
//
#include <hip/hip_runtime.h>

#define DD 64
#define BSHIFT 12              // 4096 nodes per bucket
#define BNODES (1 << BSHIFT)
#define NBMAX 256

typedef float f32x4 __attribute__((ext_vector_type(4)));
typedef unsigned int u32x2 __attribute__((ext_vector_type(2)));
typedef unsigned int u32;
typedef unsigned short u16;

static inline int cdiv(long long a, int b) { return (int)((a + b - 1) / b); }

// ---- bf16 helpers (RNE) ----
__device__ inline f32x4 bf4_to_f(u32x2 v) {
    f32x4 r;
    r.x = __uint_as_float(v.x << 16);
    r.y = __uint_as_float(v.x & 0xFFFF0000u);
    r.z = __uint_as_float(v.y << 16);
    r.w = __uint_as_float(v.y & 0xFFFF0000u);
    return r;
}
__device__ inline u32 pack_bf2(float a, float b) {
    u32 ua = __float_as_uint(a);
    u32 ub = __float_as_uint(b);
    u32 lo = (ua + 0x7FFFu + ((ua >> 16) & 1u)) >> 16;
    u32 hi = (ub + 0x7FFFu + ((ub >> 16) & 1u)) >> 16;
    return lo | (hi << 16);
}
__device__ inline u32x2 pack_bf4(f32x4 v) {
    u32x2 r;
    r.x = pack_bf2(v.x, v.y);
    r.y = pack_bf2(v.z, v.w);
    return r;
}

// bcur[b] = b*CAP  (fixed-capacity staging cursors)
__global__ void k_initcur(int* __restrict__ bcur, int NB, int CAP) {
    int i = threadIdx.x;
    if (i < NB) bcur[i] = i * CAP;
}

// scatter packed records (local_target<<20 | neighbor) into fixed-cap bucket staging
// REQUIRES n < 2^20 (n = 700k) and BSHIFT <= 12.
__global__ void k_bscatter(const int* __restrict__ edges, int E, int nu,
                           int* __restrict__ bcur, u32* __restrict__ stg, int CH) {
    __shared__ int h[NBMAX];
    __shared__ int base[NBMAX];
    int tid = threadIdx.x;
    h[tid] = 0;
    __syncthreads();
    int e0 = blockIdx.x * CH;
    int e1 = min(e0 + CH, E);
    for (int e = e0 + tid; e < e1; e += blockDim.x) {
        atomicAdd(&h[edges[e] >> BSHIFT], 1);
        atomicAdd(&h[(nu + edges[E + e]) >> BSHIFT], 1);
    }
    __syncthreads();
    {
        int c = h[tid];
        base[tid] = c ? atomicAdd(&bcur[tid], c) : 0;
        h[tid] = 0;
    }
    __syncthreads();
    for (int e = e0 + tid; e < e1; e += blockDim.x) {
        u32 u = (u32)edges[e];
        u32 w = (u32)(nu + edges[E + e]);
        int b1 = u >> BSHIFT;
        int b2 = w >> BSHIFT;
        int i1 = atomicAdd(&h[b1], 1);
        stg[(size_t)base[b1] + i1] = ((u & (BNODES - 1)) << 20) | w;
        int i2 = atomicAdd(&h[b2], 1);
        stg[(size_t)base[b2] + i2] = ((w & (BNODES - 1)) << 20) | u;
    }
}

// compact adj bases from post-scatter cursors
__global__ void k_bscan(const int* __restrict__ bcur, int* __restrict__ bbase,
                        int NB, int CAP) {
    if (threadIdx.x == 0) {
        int run = 0;
        for (int i = 0; i < NB; i++) {
            bbase[i] = run;
            run += bcur[i] - i * CAP;
        }
    }
}

// one block per bucket: LDS counting sort -> compact adj; emits ptr, deg16, dinv.
__global__ void k_bsort(const u32* __restrict__ stg, const int* __restrict__ bcur,
                        const int* __restrict__ bbase, int* __restrict__ adj,
                        int* __restrict__ ptr, u16* __restrict__ deg16,
                        float* __restrict__ dinv, int n, int CAP) {
    __shared__ int cnt[BNODES];
    __shared__ int tsum[256];
    int b = blockIdx.x;
    int tid = threadIdx.x;
    int node0 = b << BSHIFT;
    size_t s = (size_t)b * CAP;
    size_t e = (size_t)bcur[b];
    int w0 = bbase[b];

    for (int i = tid; i < BNODES; i += 256) cnt[i] = 0;
    __syncthreads();
    for (size_t i = s + tid; i < e; i += 256) {
        atomicAdd(&cnt[stg[i] >> 20], 1);
    }
    __syncthreads();

    int base16 = tid * 16;
    int loc = 0;
#pragma unroll
    for (int j = 0; j < 16; j++) loc += cnt[base16 + j];
    tsum[tid] = loc;
    __syncthreads();
    for (int off = 1; off < 256; off <<= 1) {
        int t = (tid >= off) ? tsum[tid - off] : 0;
        __syncthreads();
        tsum[tid] += t;
        __syncthreads();
    }
    int run = (tid > 0) ? tsum[tid - 1] : 0;
#pragma unroll
    for (int j = 0; j < 16; j++) {
        int node = node0 + base16 + j;
        int c = cnt[base16 + j];
        cnt[base16 + j] = run;
        if (node < n) {
            ptr[node] = w0 + run;
            deg16[node] = (u16)c;
            dinv[node] = rsqrtf((float)(c + 1));   // +1 self loop
        }
        run += c;
    }
    __syncthreads();

    for (size_t i = s + tid; i < e; i += 256) {
        u32 rec = stg[i];
        int pos = atomicAdd(&cnt[rec >> 20], 1);
        adj[w0 + pos] = (int)(rec & 0xFFFFFu);
    }
}

// g0 = dinv .* x  (bf16 packed); NT loads of the single-use f32 weights
__global__ void k_init(const float* __restrict__ uw, const float* __restrict__ iw,
                       const float* __restrict__ dinv, u16* __restrict__ g,
                       int nQuads, int nuQ) {
    int i = blockIdx.x * blockDim.x + threadIdx.x;
    if (i < nQuads) {
        f32x4 x = (i < nuQ) ? __builtin_nontemporal_load((const f32x4*)uw + i)
                            : __builtin_nontemporal_load((const f32x4*)iw + (i - nuQ));
        float s = dinv[i >> 4];
        ((u32x2*)g)[i] = pack_bf4(s * x);
    }
}

// quarter-wave (16 lanes) per node, bf16 rows (u32x2 = 4 bf16 per lane).
// gn = dinv[c]^2 * (g[c] + sum_{r in N(c)} g[r])      (layers 1 and 2)
__global__ void k_gatherb(const int* __restrict__ ptr, const u16* __restrict__ deg16,
                          const int* __restrict__ adj, const float* __restrict__ dinv,
                          const u16* __restrict__ g, u16* __restrict__ gn, int n) {
    int t = blockIdx.x * blockDim.x + threadIdx.x;
    int lane = threadIdx.x & 63;
    int j = lane & 15;
    int c = (t >> 6) * 4 + (lane >> 4);
    bool valid = (c < n);
    int cc = valid ? c : (n - 1);
    float dc = __builtin_nontemporal_load(dinv + cc);
    int s = __builtin_nontemporal_load(ptr + cc);
    int deg = __builtin_nontemporal_load(deg16 + cc);

    f32x4 acc = bf4_to_f(((const u32x2*)(g + (size_t)cc * DD))[j]);

    int grpbase = lane & 48;
    for (int base = 0; base < deg; base += 16) {
        int cnt = deg - base; if (cnt > 16) cnt = 16;
        int myr = (j < cnt) ? __builtin_nontemporal_load(adj + s + base + j) : 0;
        int k = 0;
        for (; k + 4 <= cnt; k += 4) {
            int r0 = __shfl(myr, grpbase + k, 64);
            int r1 = __shfl(myr, grpbase + k + 1, 64);
            int r2 = __shfl(myr, grpbase + k + 2, 64);
            int r3 = __shfl(myr, grpbase + k + 3, 64);
            u32x2 v0 = ((const u32x2*)(g + (size_t)r0 * DD))[j];
            u32x2 v1 = ((const u32x2*)(g + (size_t)r1 * DD))[j];
            u32x2 v2 = ((const u32x2*)(g + (size_t)r2 * DD))[j];
            u32x2 v3 = ((const u32x2*)(g + (size_t)r3 * DD))[j];
            acc += bf4_to_f(v0); acc += bf4_to_f(v1);
            acc += bf4_to_f(v2); acc += bf4_to_f(v3);
        }
        for (; k < cnt; k++) {
            int r = __shfl(myr, grpbase + k, 64);
            acc += bf4_to_f(((const u32x2*)(g + (size_t)r * DD))[j]);
        }
    }

    if (!valid) return;
    f32x4 gnv = (dc * dc) * acc;     // dinv * h_next
    __builtin_nontemporal_store(pack_bf4(gnv), (u32x2*)(gn + (size_t)cc * DD) + j);
}

// epilogue: h3 in-register; x,h1,h2 reconstructed from g0,g1,g2 (all bf16).
// g0/g1 are never neighbor-read here -> NT loads keep L2 for g2 neighbor rows.
__global__ void k_gfinal(const int* __restrict__ ptr, const u16* __restrict__ deg16,
                         const int* __restrict__ adj, const float* __restrict__ dinv,
                         const u16* __restrict__ g2, const u16* __restrict__ g1,
                         const u16* __restrict__ g0, const float* __restrict__ aw,
                         float* __restrict__ out, int n, int nu) {
    int t = blockIdx.x * blockDim.x + threadIdx.x;
    int lane = threadIdx.x & 63;
    int j = lane & 15;
    int c = (t >> 6) * 4 + (lane >> 4);
    bool valid = (c < n);
    int cc = valid ? c : (n - 1);
    float dc = __builtin_nontemporal_load(dinv + cc);
    int s = __builtin_nontemporal_load(ptr + cc);
    int deg = __builtin_nontemporal_load(deg16 + cc);

    f32x4 g2c = bf4_to_f(((const u32x2*)(g2 + (size_t)cc * DD))[j]);
    f32x4 acc = g2c;

    int grpbase = lane & 48;
    for (int base = 0; base < deg; base += 16) {
        int cnt = deg - base; if (cnt > 16) cnt = 16;
        int myr = (j < cnt) ? __builtin_nontemporal_load(adj + s + base + j) : 0;
        int k = 0;
        for (; k + 4 <= cnt; k += 4) {
            int r0 = __shfl(myr, grpbase + k, 64);
            int r1 = __shfl(myr, grpbase + k + 1, 64);
            int r2 = __shfl(myr, grpbase + k + 2, 64);
            int r3 = __shfl(myr, grpbase + k + 3, 64);
            u32x2 v0 = ((const u32x2*)(g2 + (size_t)r0 * DD))[j];
            u32x2 v1 = ((const u32x2*)(g2 + (size_t)r1 * DD))[j];
            u32x2 v2 = ((const u32x2*)(g2 + (size_t)r2 * DD))[j];
            u32x2 v3 = ((const u32x2*)(g2 + (size_t)r3 * DD))[j];
            acc += bf4_to_f(v0); acc += bf4_to_f(v1);
            acc += bf4_to_f(v2); acc += bf4_to_f(v3);
        }
        for (; k < cnt; k++) {
            int r = __shfl(myr, grpbase + k, 64);
            acc += bf4_to_f(((const u32x2*)(g2 + (size_t)r * DD))[j]);
        }
    }

    if (!valid) return;
    f32x4 h3 = dc * acc;
    float sq = sqrtf((float)(deg + 1));   // 1/dc
    f32x4 xr = bf4_to_f(__builtin_nontemporal_load((const u32x2*)(g0 + (size_t)cc * DD) + j)) * sq;
    f32x4 h1 = bf4_to_f(__builtin_nontemporal_load((const u32x2*)(g1 + (size_t)cc * DD) + j)) * sq;
    f32x4 h2 = g2c * sq;
    f32x4 interest = (xr + h1 + h2 + h3) * 0.25f;
    f32x4 o;
    if (c < nu) {
        float a0 = aw[0], a1 = aw[1];
        float m = fmaxf(a0, a1);
        float e0 = expf(a0 - m), e1 = expf(a1 - m);
        float al0 = e0 / (e0 + e1);
        o = al0 * interest + (1.0f - al0) * xr;
    } else {
        o = interest;
    }
    __builtin_nontemporal_store(o, (f32x4*)(out + (size_t)cc * DD) + j);
}

extern "C" void kernel_launch(void* const* d_in, const int* in_sizes, int n_in,
                              void* d_out, int out_size, void* d_ws, size_t ws_size,
                              hipStream_t stream) {
    const int* edges = (const int*)d_in[0];   // (2,E)
    const float* uw = (const float*)d_in[1];  // (nu,64)
    const float* iw = (const float*)d_in[2];  // (ni,64)
    const float* aw = (const float*)d_in[3];  // (2,)
    float* out = (float*)d_out;

    const int E = in_sizes[0] / 2;
    const int nu = in_sizes[1] / DD;
    const int ni = in_sizes[2] / DD;
    const int n = nu + ni;
    const int nElem = n * DD;
    const int twoE = 2 * E;
    const int NB = (n + BNODES - 1) >> BSHIFT;
    // fixed staging capacity per bucket (records); slot holds nElem/2 records total
    const int CAP = (nElem / 2) / NB;          // ~131k for n=700k, worst bucket ~42k

    char* ws = (char*)d_ws;
    size_t off = 0;
    auto alloc = [&](size_t bytes) { size_t r = off; off = (off + bytes + 255) & ~(size_t)255; return r; };
    int* ptr    = (int*)(ws + alloc((size_t)n * 4));
    float* dinv = (float*)(ws + alloc((size_t)n * 4));
    u16* deg16  = (u16*)(ws + alloc((size_t)n * 2));
    int* adj    = (int*)(ws + alloc((size_t)twoE * 4));
    int* bcur   = (int*)(ws + alloc(NBMAX * 4));
    int* bbase  = (int*)(ws + alloc((NBMAX + 1) * 4));
    u16* g0     = (u16*)(ws + alloc((size_t)nElem * 2));
    u16* g1     = (u16*)(ws + alloc((size_t)nElem * 2));
    // g2 slot also hosts u32 staging records (stg dead before layer-2 writes g2)
    u16* g2     = (u16*)(ws + alloc((size_t)nElem * 2));
    u32* stg    = (u32*)g2;

    const int B = 256;
    const int nQuads = nElem / 4;
    const int nuQ = nu * DD / 4;
    const int gI  = cdiv(nQuads, B);
    const int gW4 = cdiv((long long)cdiv(n, 4) * 64, B);
    const int CH  = 4096;
    const int gSC = cdiv(E, CH);

    // bucketed CSR build (fixed-capacity staging; no pre-histogram pass)
    k_initcur<<<1, NBMAX, 0, stream>>>(bcur, NB, CAP);
    k_bscatter<<<gSC, NBMAX, 0, stream>>>(edges, E, nu, bcur, stg, CH);
    k_bscan<<<1, 64, 0, stream>>>(bcur, bbase, NB, CAP);
    k_bsort<<<NB, 256, 0, stream>>>(stg, bcur, bbase, adj, ptr, deg16, dinv, n, CAP);

    // g0 = dinv .* x (bf16)
    k_init<<<gI, B, 0, stream>>>(uw, iw, dinv, g0, nQuads, nuQ);

    // layer 1: g0 -> g1
    k_gatherb<<<gW4, B, 0, stream>>>(ptr, deg16, adj, dinv, g0, g1, n);
    // layer 2: g1 -> g2
    k_gatherb<<<gW4, B, 0, stream>>>(ptr, deg16, adj, dinv, g1, g2, n);
    // layer 3 + fused acc/epilogue (x,h1,h2 from g0,g1,g2): g2 -> out
    k_gfinal<<<gW4, B, 0, stream>>>(ptr, deg16, adj, dinv, g2, g1, g0, aw, out, n, nu);
}

// Round 13
// 564.040 us; speedup vs baseline: 1.0449x; 1.0449x over previous
//
#include <hip/hip_runtime.h>

#define DD 64
#define BSHIFT 12              // 4096 nodes per bucket
#define BNODES (1 << BSHIFT)
#define NBMAX 256

typedef float f32x4 __attribute__((ext_vector_type(4)));
typedef unsigned int u32x2 __attribute__((ext_vector_type(2)));
typedef unsigned int u32;
typedef unsigned short u16;

static inline int cdiv(long long a, int b) { return (int)((a + b - 1) / b); }

// ---- bf16 helpers (RNE) ----
__device__ inline f32x4 bf4_to_f(u32x2 v) {
    f32x4 r;
    r.x = __uint_as_float(v.x << 16);
    r.y = __uint_as_float(v.x & 0xFFFF0000u);
    r.z = __uint_as_float(v.y << 16);
    r.w = __uint_as_float(v.y & 0xFFFF0000u);
    return r;
}
__device__ inline u32 pack_bf2(float a, float b) {
    u32 ua = __float_as_uint(a);
    u32 ub = __float_as_uint(b);
    u32 lo = (ua + 0x7FFFu + ((ua >> 16) & 1u)) >> 16;
    u32 hi = (ub + 0x7FFFu + ((ub >> 16) & 1u)) >> 16;
    return lo | (hi << 16);
}
__device__ inline u32x2 pack_bf4(f32x4 v) {
    u32x2 r;
    r.x = pack_bf2(v.x, v.y);
    r.y = pack_bf2(v.z, v.w);
    return r;
}

// bcur[b] = b*CAP  (fixed-capacity staging cursors)
__global__ void k_initcur(int* __restrict__ bcur, int NB, int CAP) {
    int i = threadIdx.x;
    if (i < NB) bcur[i] = i * CAP;
}

// scatter packed records (local_target<<20 | neighbor) into fixed-cap bucket staging
// REQUIRES n < 2^20 (n = 700k) and BSHIFT <= 12.
__global__ void k_bscatter(const int* __restrict__ edges, int E, int nu,
                           int* __restrict__ bcur, u32* __restrict__ stg, int CH) {
    __shared__ int h[NBMAX];
    __shared__ int base[NBMAX];
    int tid = threadIdx.x;
    h[tid] = 0;
    __syncthreads();
    int e0 = blockIdx.x * CH;
    int e1 = min(e0 + CH, E);
    for (int e = e0 + tid; e < e1; e += blockDim.x) {
        atomicAdd(&h[edges[e] >> BSHIFT], 1);
        atomicAdd(&h[(nu + edges[E + e]) >> BSHIFT], 1);
    }
    __syncthreads();
    {
        int c = h[tid];
        base[tid] = c ? atomicAdd(&bcur[tid], c) : 0;
        h[tid] = 0;
    }
    __syncthreads();
    for (int e = e0 + tid; e < e1; e += blockDim.x) {
        u32 u = (u32)edges[e];
        u32 w = (u32)(nu + edges[E + e]);
        int b1 = u >> BSHIFT;
        int b2 = w >> BSHIFT;
        int i1 = atomicAdd(&h[b1], 1);
        stg[(size_t)base[b1] + i1] = ((u & (BNODES - 1)) << 20) | w;
        int i2 = atomicAdd(&h[b2], 1);
        stg[(size_t)base[b2] + i2] = ((w & (BNODES - 1)) << 20) | u;
    }
}

// compact adj bases from post-scatter cursors
__global__ void k_bscan(const int* __restrict__ bcur, int* __restrict__ bbase,
                        int NB, int CAP) {
    if (threadIdx.x == 0) {
        int run = 0;
        for (int i = 0; i < NB; i++) {
            bbase[i] = run;
            run += bcur[i] - i * CAP;
        }
    }
}

// one block per bucket: LDS counting sort -> compact adj; emits pd = {ptr, deg}.
__global__ void k_bsort(const u32* __restrict__ stg, const int* __restrict__ bcur,
                        const int* __restrict__ bbase, int* __restrict__ adj,
                        int2* __restrict__ pd, int n, int CAP) {
    __shared__ int cnt[BNODES];
    __shared__ int tsum[256];
    int b = blockIdx.x;
    int tid = threadIdx.x;
    int node0 = b << BSHIFT;
    size_t s = (size_t)b * CAP;
    size_t e = (size_t)bcur[b];
    int w0 = bbase[b];

    for (int i = tid; i < BNODES; i += 256) cnt[i] = 0;
    __syncthreads();
    for (size_t i = s + tid; i < e; i += 256) {
        atomicAdd(&cnt[stg[i] >> 20], 1);
    }
    __syncthreads();

    int base16 = tid * 16;
    int loc = 0;
#pragma unroll
    for (int j = 0; j < 16; j++) loc += cnt[base16 + j];
    tsum[tid] = loc;
    __syncthreads();
    for (int off = 1; off < 256; off <<= 1) {
        int t = (tid >= off) ? tsum[tid - off] : 0;
        __syncthreads();
        tsum[tid] += t;
        __syncthreads();
    }
    int run = (tid > 0) ? tsum[tid - 1] : 0;
#pragma unroll
    for (int j = 0; j < 16; j++) {
        int node = node0 + base16 + j;
        int c = cnt[base16 + j];
        cnt[base16 + j] = run;
        if (node < n) {
            pd[node] = make_int2(w0 + run, c);
        }
        run += c;
    }
    __syncthreads();

    for (size_t i = s + tid; i < e; i += 256) {
        u32 rec = stg[i];
        int pos = atomicAdd(&cnt[rec >> 20], 1);
        adj[w0 + pos] = (int)(rec & 0xFFFFFu);
    }
}

// g0 = dinv .* x  (bf16 packed); dinv computed from pd.deg
__global__ void k_init(const float* __restrict__ uw, const float* __restrict__ iw,
                       const int2* __restrict__ pd, u16* __restrict__ g,
                       int nQuads, int nuQ) {
    int i = blockIdx.x * blockDim.x + threadIdx.x;
    if (i < nQuads) {
        f32x4 x = (i < nuQ) ? ((const f32x4*)uw)[i] : ((const f32x4*)iw)[i - nuQ];
        float s = rsqrtf((float)(pd[i >> 4].y + 1));
        ((u32x2*)g)[i] = pack_bf4(s * x);
    }
}

// quarter-wave (16 lanes) per node, bf16 rows (u32x2 = 4 bf16 per lane).
// gn = dinv[c]^2 * (g[c] + sum_{r in N(c)} g[r])      (layers 1 and 2)
__global__ void k_gatherb(const int2* __restrict__ pd, const int* __restrict__ adj,
                          const u16* __restrict__ g, u16* __restrict__ gn, int n) {
    int t = blockIdx.x * blockDim.x + threadIdx.x;
    int lane = threadIdx.x & 63;
    int j = lane & 15;
    int c = (t >> 6) * 4 + (lane >> 4);
    bool valid = (c < n);
    int cc = valid ? c : (n - 1);
    int2 pdc = pd[cc];
    int s = pdc.x;
    int deg = pdc.y;
    float di = 1.0f / (float)(deg + 1);   // dinv^2 exactly

    f32x4 acc = bf4_to_f(((const u32x2*)(g + (size_t)cc * DD))[j]);

    int grpbase = lane & 48;
    for (int base = 0; base < deg; base += 16) {
        int cnt = deg - base; if (cnt > 16) cnt = 16;
        int myr = (j < cnt) ? adj[s + base + j] : 0;
        int k = 0;
        for (; k + 4 <= cnt; k += 4) {
            int r0 = __shfl(myr, grpbase + k, 64);
            int r1 = __shfl(myr, grpbase + k + 1, 64);
            int r2 = __shfl(myr, grpbase + k + 2, 64);
            int r3 = __shfl(myr, grpbase + k + 3, 64);
            u32x2 v0 = ((const u32x2*)(g + (size_t)r0 * DD))[j];
            u32x2 v1 = ((const u32x2*)(g + (size_t)r1 * DD))[j];
            u32x2 v2 = ((const u32x2*)(g + (size_t)r2 * DD))[j];
            u32x2 v3 = ((const u32x2*)(g + (size_t)r3 * DD))[j];
            acc += bf4_to_f(v0); acc += bf4_to_f(v1);
            acc += bf4_to_f(v2); acc += bf4_to_f(v3);
        }
        for (; k < cnt; k++) {
            int r = __shfl(myr, grpbase + k, 64);
            acc += bf4_to_f(((const u32x2*)(g + (size_t)r * DD))[j]);
        }
    }

    if (!valid) return;
    f32x4 gnv = di * acc;     // dinv * h_next = dinv^2 * (g_c + sum g_r)
    __builtin_nontemporal_store(pack_bf4(gnv), (u32x2*)(gn + (size_t)cc * DD) + j);
}

// epilogue: h3 in-register; x,h1,h2 reconstructed from g0,g1,g2 (all bf16).
__global__ void k_gfinal(const int2* __restrict__ pd, const int* __restrict__ adj,
                         const u16* __restrict__ g2, const u16* __restrict__ g1,
                         const u16* __restrict__ g0, const float* __restrict__ aw,
                         float* __restrict__ out, int n, int nu) {
    int t = blockIdx.x * blockDim.x + threadIdx.x;
    int lane = threadIdx.x & 63;
    int j = lane & 15;
    int c = (t >> 6) * 4 + (lane >> 4);
    bool valid = (c < n);
    int cc = valid ? c : (n - 1);
    int2 pdc = pd[cc];
    int s = pdc.x;
    int deg = pdc.y;
    float dc = rsqrtf((float)(deg + 1));

    f32x4 g2c = bf4_to_f(((const u32x2*)(g2 + (size_t)cc * DD))[j]);
    f32x4 acc = g2c;

    int grpbase = lane & 48;
    for (int base = 0; base < deg; base += 16) {
        int cnt = deg - base; if (cnt > 16) cnt = 16;
        int myr = (j < cnt) ? adj[s + base + j] : 0;
        int k = 0;
        for (; k + 4 <= cnt; k += 4) {
            int r0 = __shfl(myr, grpbase + k, 64);
            int r1 = __shfl(myr, grpbase + k + 1, 64);
            int r2 = __shfl(myr, grpbase + k + 2, 64);
            int r3 = __shfl(myr, grpbase + k + 3, 64);
            u32x2 v0 = ((const u32x2*)(g2 + (size_t)r0 * DD))[j];
            u32x2 v1 = ((const u32x2*)(g2 + (size_t)r1 * DD))[j];
            u32x2 v2 = ((const u32x2*)(g2 + (size_t)r2 * DD))[j];
            u32x2 v3 = ((const u32x2*)(g2 + (size_t)r3 * DD))[j];
            acc += bf4_to_f(v0); acc += bf4_to_f(v1);
            acc += bf4_to_f(v2); acc += bf4_to_f(v3);
        }
        for (; k < cnt; k++) {
            int r = __shfl(myr, grpbase + k, 64);
            acc += bf4_to_f(((const u32x2*)(g2 + (size_t)r * DD))[j]);
        }
    }

    if (!valid) return;
    f32x4 h3 = dc * acc;
    float sq = sqrtf((float)(deg + 1));   // 1/dc
    f32x4 xr = bf4_to_f(((const u32x2*)(g0 + (size_t)cc * DD))[j]) * sq;
    f32x4 h1 = bf4_to_f(((const u32x2*)(g1 + (size_t)cc * DD))[j]) * sq;
    f32x4 h2 = g2c * sq;
    f32x4 interest = (xr + h1 + h2 + h3) * 0.25f;
    f32x4 o;
    if (c < nu) {
        float a0 = aw[0], a1 = aw[1];
        float m = fmaxf(a0, a1);
        float e0 = expf(a0 - m), e1 = expf(a1 - m);
        float al0 = e0 / (e0 + e1);
        o = al0 * interest + (1.0f - al0) * xr;
    } else {
        o = interest;
    }
    __builtin_nontemporal_store(o, (f32x4*)(out + (size_t)cc * DD) + j);
}

extern "C" void kernel_launch(void* const* d_in, const int* in_sizes, int n_in,
                              void* d_out, int out_size, void* d_ws, size_t ws_size,
                              hipStream_t stream) {
    const int* edges = (const int*)d_in[0];   // (2,E)
    const float* uw = (const float*)d_in[1];  // (nu,64)
    const float* iw = (const float*)d_in[2];  // (ni,64)
    const float* aw = (const float*)d_in[3];  // (2,)
    float* out = (float*)d_out;

    const int E = in_sizes[0] / 2;
    const int nu = in_sizes[1] / DD;
    const int ni = in_sizes[2] / DD;
    const int n = nu + ni;
    const int nElem = n * DD;
    const int twoE = 2 * E;
    const int NB = (n + BNODES - 1) >> BSHIFT;
    const int CAP = (nElem / 2) / NB;          // fixed staging cap per bucket

    char* ws = (char*)d_ws;
    size_t off = 0;
    auto alloc = [&](size_t bytes) { size_t r = off; off = (off + bytes + 255) & ~(size_t)255; return r; };
    int2* pd    = (int2*)(ws + alloc((size_t)n * 8));
    int* adj    = (int*)(ws + alloc((size_t)twoE * 4));
    int* bcur   = (int*)(ws + alloc(NBMAX * 4));
    int* bbase  = (int*)(ws + alloc((NBMAX + 1) * 4));
    u16* g0     = (u16*)(ws + alloc((size_t)nElem * 2));
    u16* g1     = (u16*)(ws + alloc((size_t)nElem * 2));
    // g2 slot also hosts u32 staging records (stg dead before layer-2 writes g2)
    u16* g2     = (u16*)(ws + alloc((size_t)nElem * 2));
    u32* stg    = (u32*)g2;

    const int B = 256;
    const int nQuads = nElem / 4;
    const int nuQ = nu * DD / 4;
    const int gI  = cdiv(nQuads, B);
    const int gW4 = cdiv((long long)cdiv(n, 4) * 64, B);
    const int CH  = 4096;
    const int gSC = cdiv(E, CH);

    // bucketed CSR build (fixed-capacity staging; no pre-histogram pass)
    k_initcur<<<1, NBMAX, 0, stream>>>(bcur, NB, CAP);
    k_bscatter<<<gSC, NBMAX, 0, stream>>>(edges, E, nu, bcur, stg, CH);
    k_bscan<<<1, 64, 0, stream>>>(bcur, bbase, NB, CAP);
    k_bsort<<<NB, 256, 0, stream>>>(stg, bcur, bbase, adj, pd, n, CAP);

    // g0 = dinv .* x (bf16)
    k_init<<<gI, B, 0, stream>>>(uw, iw, pd, g0, nQuads, nuQ);

    // layer 1: g0 -> g1
    k_gatherb<<<gW4, B, 0, stream>>>(pd, adj, g0, g1, n);
    // layer 2: g1 -> g2
    k_gatherb<<<gW4, B, 0, stream>>>(pd, adj, g1, g2, n);
    // layer 3 + fused acc/epilogue (x,h1,h2 from g0,g1,g2): g2 -> out
    k_gfinal<<<gW4, B, 0, stream>>>(pd, adj, g2, g1, g0, aw, out, n, nu);
}

// Round 14
// 536.355 us; speedup vs baseline: 1.0988x; 1.0516x over previous
//
#include <hip/hip_runtime.h>

#define DD 64
#define BSHIFT 12              // 4096 nodes per bucket
#define BNODES (1 << BSHIFT)
#define NBMAX 256

typedef float f32x4 __attribute__((ext_vector_type(4)));
typedef float f32x8 __attribute__((ext_vector_type(8)));
typedef unsigned int u32x2 __attribute__((ext_vector_type(2)));
typedef unsigned int u32x4 __attribute__((ext_vector_type(4)));
typedef unsigned int u32;
typedef unsigned short u16;

static inline int cdiv(long long a, int b) { return (int)((a + b - 1) / b); }

// ---- bf16 helpers (RNE) ----
__device__ inline f32x8 bf8_to_f(u32x4 v) {
    f32x8 r;
    r.s0 = __uint_as_float(v.x << 16);
    r.s1 = __uint_as_float(v.x & 0xFFFF0000u);
    r.s2 = __uint_as_float(v.y << 16);
    r.s3 = __uint_as_float(v.y & 0xFFFF0000u);
    r.s4 = __uint_as_float(v.z << 16);
    r.s5 = __uint_as_float(v.z & 0xFFFF0000u);
    r.s6 = __uint_as_float(v.w << 16);
    r.s7 = __uint_as_float(v.w & 0xFFFF0000u);
    return r;
}
__device__ inline u32 pack_bf2(float a, float b) {
    u32 ua = __float_as_uint(a);
    u32 ub = __float_as_uint(b);
    u32 lo = (ua + 0x7FFFu + ((ua >> 16) & 1u)) >> 16;
    u32 hi = (ub + 0x7FFFu + ((ub >> 16) & 1u)) >> 16;
    return lo | (hi << 16);
}
__device__ inline u32x4 pack_bf8(f32x8 v) {
    u32x4 r;
    r.x = pack_bf2(v.s0, v.s1);
    r.y = pack_bf2(v.s2, v.s3);
    r.z = pack_bf2(v.s4, v.s5);
    r.w = pack_bf2(v.s6, v.s7);
    return r;
}
__device__ inline u32x2 pack_bf4(f32x4 v) {
    u32x2 r;
    r.x = pack_bf2(v.x, v.y);
    r.y = pack_bf2(v.z, v.w);
    return r;
}

// bcur[b] = b*CAP  (fixed-capacity staging cursors)
__global__ void k_initcur(int* __restrict__ bcur, int NB, int CAP) {
    int i = threadIdx.x;
    if (i < NB) bcur[i] = i * CAP;
}

// scatter packed records (local_target<<20 | neighbor) into fixed-cap bucket staging
// REQUIRES n < 2^20 (n = 700k) and BSHIFT <= 12.
__global__ void k_bscatter(const int* __restrict__ edges, int E, int nu,
                           int* __restrict__ bcur, u32* __restrict__ stg, int CH) {
    __shared__ int h[NBMAX];
    __shared__ int base[NBMAX];
    int tid = threadIdx.x;
    h[tid] = 0;
    __syncthreads();
    int e0 = blockIdx.x * CH;
    int e1 = min(e0 + CH, E);
    for (int e = e0 + tid; e < e1; e += blockDim.x) {
        atomicAdd(&h[edges[e] >> BSHIFT], 1);
        atomicAdd(&h[(nu + edges[E + e]) >> BSHIFT], 1);
    }
    __syncthreads();
    {
        int c = h[tid];
        base[tid] = c ? atomicAdd(&bcur[tid], c) : 0;
        h[tid] = 0;
    }
    __syncthreads();
    for (int e = e0 + tid; e < e1; e += blockDim.x) {
        u32 u = (u32)edges[e];
        u32 w = (u32)(nu + edges[E + e]);
        int b1 = u >> BSHIFT;
        int b2 = w >> BSHIFT;
        int i1 = atomicAdd(&h[b1], 1);
        stg[(size_t)base[b1] + i1] = ((u & (BNODES - 1)) << 20) | w;
        int i2 = atomicAdd(&h[b2], 1);
        stg[(size_t)base[b2] + i2] = ((w & (BNODES - 1)) << 20) | u;
    }
}

// compact adj bases from post-scatter cursors
__global__ void k_bscan(const int* __restrict__ bcur, int* __restrict__ bbase,
                        int NB, int CAP) {
    if (threadIdx.x == 0) {
        int run = 0;
        for (int i = 0; i < NB; i++) {
            bbase[i] = run;
            run += bcur[i] - i * CAP;
        }
    }
}

// one block per bucket: LDS counting sort -> compact adj; emits pd = {ptr, deg}.
__global__ void k_bsort(const u32* __restrict__ stg, const int* __restrict__ bcur,
                        const int* __restrict__ bbase, int* __restrict__ adj,
                        int2* __restrict__ pd, int n, int CAP) {
    __shared__ int cnt[BNODES];
    __shared__ int tsum[256];
    int b = blockIdx.x;
    int tid = threadIdx.x;
    int node0 = b << BSHIFT;
    size_t s = (size_t)b * CAP;
    size_t e = (size_t)bcur[b];
    int w0 = bbase[b];

    for (int i = tid; i < BNODES; i += 256) cnt[i] = 0;
    __syncthreads();
    for (size_t i = s + tid; i < e; i += 256) {
        atomicAdd(&cnt[stg[i] >> 20], 1);
    }
    __syncthreads();

    int base16 = tid * 16;
    int loc = 0;
#pragma unroll
    for (int j = 0; j < 16; j++) loc += cnt[base16 + j];
    tsum[tid] = loc;
    __syncthreads();
    for (int off = 1; off < 256; off <<= 1) {
        int t = (tid >= off) ? tsum[tid - off] : 0;
        __syncthreads();
        tsum[tid] += t;
        __syncthreads();
    }
    int run = (tid > 0) ? tsum[tid - 1] : 0;
#pragma unroll
    for (int j = 0; j < 16; j++) {
        int node = node0 + base16 + j;
        int c = cnt[base16 + j];
        cnt[base16 + j] = run;
        if (node < n) {
            pd[node] = make_int2(w0 + run, c);
        }
        run += c;
    }
    __syncthreads();

    for (size_t i = s + tid; i < e; i += 256) {
        u32 rec = stg[i];
        int pos = atomicAdd(&cnt[rec >> 20], 1);
        adj[w0 + pos] = (int)(rec & 0xFFFFFu);
    }
}

// g0 = dinv .* x  (bf16 packed); dinv computed from pd.deg
__global__ void k_init(const float* __restrict__ uw, const float* __restrict__ iw,
                       const int2* __restrict__ pd, u16* __restrict__ g,
                       int nQuads, int nuQ) {
    int i = blockIdx.x * blockDim.x + threadIdx.x;
    if (i < nQuads) {
        f32x4 x = (i < nuQ) ? ((const f32x4*)uw)[i] : ((const f32x4*)iw)[i - nuQ];
        float s = rsqrtf((float)(pd[i >> 4].y + 1));
        ((u32x2*)g)[i] = pack_bf4(s * x);
    }
}

// eighth-wave (8 lanes) per node, bf16 rows (u32x4 = 8 bf16 = 16B per lane).
// gn = dinv[c]^2 * (g[c] + sum_{r in N(c)} g[r])      (layers 1 and 2)
__global__ void k_gatherb(const int2* __restrict__ pd, const int* __restrict__ adj,
                          const u16* __restrict__ g, u16* __restrict__ gn, int n) {
    int t = blockIdx.x * blockDim.x + threadIdx.x;
    int lane = threadIdx.x & 63;
    int j = lane & 7;                      // dim octet (8 bf16 = 16B)
    int c = (t >> 6) * 8 + (lane >> 3);
    bool valid = (c < n);
    int cc = valid ? c : (n - 1);
    int2 pdc = pd[cc];
    int s = pdc.x;
    int deg = pdc.y;
    float di = 1.0f / (float)(deg + 1);    // dinv^2 exactly

    f32x8 acc = bf8_to_f(((const u32x4*)(g + (size_t)cc * DD))[j]);

    int grpbase = lane & 56;
    for (int base = 0; base < deg; base += 8) {
        int cnt = deg - base; if (cnt > 8) cnt = 8;
        int myr = (j < cnt) ? adj[s + base + j] : 0;
        int k = 0;
        for (; k + 4 <= cnt; k += 4) {
            int r0 = __shfl(myr, grpbase + k, 64);
            int r1 = __shfl(myr, grpbase + k + 1, 64);
            int r2 = __shfl(myr, grpbase + k + 2, 64);
            int r3 = __shfl(myr, grpbase + k + 3, 64);
            u32x4 v0 = ((const u32x4*)(g + (size_t)r0 * DD))[j];
            u32x4 v1 = ((const u32x4*)(g + (size_t)r1 * DD))[j];
            u32x4 v2 = ((const u32x4*)(g + (size_t)r2 * DD))[j];
            u32x4 v3 = ((const u32x4*)(g + (size_t)r3 * DD))[j];
            acc += bf8_to_f(v0); acc += bf8_to_f(v1);
            acc += bf8_to_f(v2); acc += bf8_to_f(v3);
        }
        for (; k < cnt; k++) {
            int r = __shfl(myr, grpbase + k, 64);
            acc += bf8_to_f(((const u32x4*)(g + (size_t)r * DD))[j]);
        }
    }

    if (!valid) return;
    f32x8 gnv = di * acc;     // dinv * h_next = dinv^2 * (g_c + sum g_r)
    __builtin_nontemporal_store(pack_bf8(gnv), (u32x4*)(gn + (size_t)cc * DD) + j);
}

// epilogue: h3 in-register; x,h1,h2 reconstructed from g0,g1,g2 (all bf16).
__global__ void k_gfinal(const int2* __restrict__ pd, const int* __restrict__ adj,
                         const u16* __restrict__ g2, const u16* __restrict__ g1,
                         const u16* __restrict__ g0, const float* __restrict__ aw,
                         float* __restrict__ out, int n, int nu) {
    int t = blockIdx.x * blockDim.x + threadIdx.x;
    int lane = threadIdx.x & 63;
    int j = lane & 7;
    int c = (t >> 6) * 8 + (lane >> 3);
    bool valid = (c < n);
    int cc = valid ? c : (n - 1);
    int2 pdc = pd[cc];
    int s = pdc.x;
    int deg = pdc.y;
    float dc = rsqrtf((float)(deg + 1));

    f32x8 g2c = bf8_to_f(((const u32x4*)(g2 + (size_t)cc * DD))[j]);
    f32x8 acc = g2c;

    int grpbase = lane & 56;
    for (int base = 0; base < deg; base += 8) {
        int cnt = deg - base; if (cnt > 8) cnt = 8;
        int myr = (j < cnt) ? adj[s + base + j] : 0;
        int k = 0;
        for (; k + 4 <= cnt; k += 4) {
            int r0 = __shfl(myr, grpbase + k, 64);
            int r1 = __shfl(myr, grpbase + k + 1, 64);
            int r2 = __shfl(myr, grpbase + k + 2, 64);
            int r3 = __shfl(myr, grpbase + k + 3, 64);
            u32x4 v0 = ((const u32x4*)(g2 + (size_t)r0 * DD))[j];
            u32x4 v1 = ((const u32x4*)(g2 + (size_t)r1 * DD))[j];
            u32x4 v2 = ((const u32x4*)(g2 + (size_t)r2 * DD))[j];
            u32x4 v3 = ((const u32x4*)(g2 + (size_t)r3 * DD))[j];
            acc += bf8_to_f(v0); acc += bf8_to_f(v1);
            acc += bf8_to_f(v2); acc += bf8_to_f(v3);
        }
        for (; k < cnt; k++) {
            int r = __shfl(myr, grpbase + k, 64);
            acc += bf8_to_f(((const u32x4*)(g2 + (size_t)r * DD))[j]);
        }
    }

    if (!valid) return;
    f32x8 h3 = dc * acc;
    float sq = sqrtf((float)(deg + 1));   // 1/dc
    f32x8 xr = bf8_to_f(((const u32x4*)(g0 + (size_t)cc * DD))[j]) * sq;
    f32x8 h1 = bf8_to_f(((const u32x4*)(g1 + (size_t)cc * DD))[j]) * sq;
    f32x8 h2 = g2c * sq;
    f32x8 interest = (xr + h1 + h2 + h3) * 0.25f;
    f32x8 o;
    if (c < nu) {
        float a0 = aw[0], a1 = aw[1];
        float m = fmaxf(a0, a1);
        float e0 = expf(a0 - m), e1 = expf(a1 - m);
        float al0 = e0 / (e0 + e1);
        o = al0 * interest + (1.0f - al0) * xr;
    } else {
        o = interest;
    }
    __builtin_nontemporal_store(o, (f32x8*)(out + (size_t)cc * DD) + j);
}

extern "C" void kernel_launch(void* const* d_in, const int* in_sizes, int n_in,
                              void* d_out, int out_size, void* d_ws, size_t ws_size,
                              hipStream_t stream) {
    const int* edges = (const int*)d_in[0];   // (2,E)
    const float* uw = (const float*)d_in[1];  // (nu,64)
    const float* iw = (const float*)d_in[2];  // (ni,64)
    const float* aw = (const float*)d_in[3];  // (2,)
    float* out = (float*)d_out;

    const int E = in_sizes[0] / 2;
    const int nu = in_sizes[1] / DD;
    const int ni = in_sizes[2] / DD;
    const int n = nu + ni;
    const int nElem = n * DD;
    const int twoE = 2 * E;
    const int NB = (n + BNODES - 1) >> BSHIFT;
    const int CAP = (nElem / 2) / NB;          // fixed staging cap per bucket

    char* ws = (char*)d_ws;
    size_t off = 0;
    auto alloc = [&](size_t bytes) { size_t r = off; off = (off + bytes + 255) & ~(size_t)255; return r; };
    int2* pd    = (int2*)(ws + alloc((size_t)n * 8));
    int* adj    = (int*)(ws + alloc((size_t)twoE * 4));
    int* bcur   = (int*)(ws + alloc(NBMAX * 4));
    int* bbase  = (int*)(ws + alloc((NBMAX + 1) * 4));
    u16* g0     = (u16*)(ws + alloc((size_t)nElem * 2));
    u16* g1     = (u16*)(ws + alloc((size_t)nElem * 2));
    // g2 slot also hosts u32 staging records (stg dead before layer-2 writes g2)
    u16* g2     = (u16*)(ws + alloc((size_t)nElem * 2));
    u32* stg    = (u32*)g2;

    const int B = 256;
    const int nQuads = nElem / 4;
    const int nuQ = nu * DD / 4;
    const int gI  = cdiv(nQuads, B);
    const int gW8 = cdiv((long long)cdiv(n, 8) * 64, B);
    const int CH  = 4096;
    const int gSC = cdiv(E, CH);

    // bucketed CSR build (fixed-capacity staging; no pre-histogram pass)
    k_initcur<<<1, NBMAX, 0, stream>>>(bcur, NB, CAP);
    k_bscatter<<<gSC, NBMAX, 0, stream>>>(edges, E, nu, bcur, stg, CH);
    k_bscan<<<1, 64, 0, stream>>>(bcur, bbase, NB, CAP);
    k_bsort<<<NB, 256, 0, stream>>>(stg, bcur, bbase, adj, pd, n, CAP);

    // g0 = dinv .* x (bf16)
    k_init<<<gI, B, 0, stream>>>(uw, iw, pd, g0, nQuads, nuQ);

    // layer 1: g0 -> g1
    k_gatherb<<<gW8, B, 0, stream>>>(pd, adj, g0, g1, n);
    // layer 2: g1 -> g2
    k_gatherb<<<gW8, B, 0, stream>>>(pd, adj, g1, g2, n);
    // layer 3 + fused acc/epilogue (x,h1,h2 from g0,g1,g2): g2 -> out
    k_gfinal<<<gW8, B, 0, stream>>>(pd, adj, g2, g1, g0, aw, out, n, nu);
}